// Round 1
// baseline (414.401 us; speedup 1.0000x reference)
//
#include <hip/hip_runtime.h>

#define NUM_DENSE 13
#define NUM_SPARSE 26
#define FEAT_NUM 40000
#define FEATURE_LENGTH (NUM_SPARSE * FEAT_NUM + NUM_DENSE)  // 1,040,013
#define KDIM 64
#define BATCH 4096

// Kernel 0: build offset indices in [slot][batch] layout (int32) so that
// accum_kernel's index reads are fully coalesced (consecutive threads = consecutive b).
__global__ void idx_kernel(const int* __restrict__ sp, int* __restrict__ idx32) {
    int tid = blockIdx.x * blockDim.x + threadIdx.x;  // tid = j*BATCH + b
    int j = tid >> 12;       // BATCH == 4096
    int b = tid & 4095;
    idx32[tid] = NUM_DENSE + j * FEAT_NUM + sp[b * NUM_SPARSE + j];
}

// Kernel 1: per (k, b) accumulate S = sum_j V[k, idx[b,j]], Q = sum_j V[..]^2.
// grid (KDIM, 4), block 1024. blockIdx.x = k -> linear%8 = k%8 so all b-quarter
// blocks of a given k land on the same XCD: the current 160KB slot window of
// row k stays L2-resident while 4096 gathers hit it (~2 hits/line).
__global__ __launch_bounds__(1024) void accum_kernel(const float* __restrict__ V,
                                                     const int* __restrict__ idx32,
                                                     float* __restrict__ S,
                                                     float* __restrict__ Q) {
    const int k = blockIdx.x;
    const int b = blockIdx.y * 1024 + threadIdx.x;
    const float* __restrict__ Vk = V + (size_t)k * FEATURE_LENGTH;
    float s = 0.f, q = 0.f;
#pragma unroll
    for (int j = 0; j < NUM_SPARSE; ++j) {
        int i = idx32[j * BATCH + b];   // coalesced, L2-hot (426 KB total)
        float v = Vk[i];                // scattered within a 160KB window
        s += v;
        q += v * v;
    }
    S[k * BATCH + b] = s;   // coalesced
    Q[k * BATCH + b] = q;
}

// Kernel 2: one wave per batch row. lane = k.
__global__ void final_kernel(const float* __restrict__ dense,
                             const float* __restrict__ w0,
                             const float* __restrict__ w,
                             const float* __restrict__ V,
                             const int* __restrict__ idx32,
                             const float* __restrict__ S,
                             const float* __restrict__ Q,
                             float* __restrict__ out) {
    const int wave = threadIdx.x >> 6;
    const int lane = threadIdx.x & 63;
    const int b = blockIdx.x * 4 + wave;
    const int k = lane;
    const float* __restrict__ Vk = V + (size_t)k * FEATURE_LENGTH;

    float sv = S[k * BATCH + b];
    float qv = Q[k * BATCH + b];
#pragma unroll
    for (int d = 0; d < NUM_DENSE; ++d) {
        float x  = dense[b * NUM_DENSE + d];  // broadcast within wave, L1-hot
        float vv = Vk[d];                     // 64x13 values, L2-hot after first waves
        sv += x * vv;
        qv += x * x * vv * vv;
    }
    float t = 0.5f * (sv * sv - qv);

    // first-order terms folded into the same reduction:
    if (lane < NUM_SPARSE) t += w[idx32[lane * BATCH + b]];          // sparse w gather
    if (lane >= 32 && lane < 32 + NUM_DENSE) {                       // dense w dot
        int d = lane - 32;
        t += dense[b * NUM_DENSE + d] * w[d];
    }

#pragma unroll
    for (int off = 32; off > 0; off >>= 1) t += __shfl_down(t, off);
    if (lane == 0) out[b] = w0[0] + t;
}

extern "C" void kernel_launch(void* const* d_in, const int* in_sizes, int n_in,
                              void* d_out, int out_size, void* d_ws, size_t ws_size,
                              hipStream_t stream) {
    const float* dense  = (const float*)d_in[0];
    const int*   sparse = (const int*)d_in[1];   // integer input -> int32 per harness convention
    const float* w0     = (const float*)d_in[2];
    const float* w      = (const float*)d_in[3];
    const float* V      = (const float*)d_in[4];
    float* out = (float*)d_out;

    char* ws = (char*)d_ws;
    int*   idx32 = (int*)ws;                              // 26*4096*4 = 425,984 B
    float* S     = (float*)(ws + (1 << 19));              // 4096*64*4 = 1 MB
    float* Q     = (float*)(ws + (1 << 19) + BATCH * KDIM * 4);

    idx_kernel<<<(NUM_SPARSE * BATCH) / 256, 256, 0, stream>>>(sparse, idx32);
    accum_kernel<<<dim3(KDIM, 4), 1024, 0, stream>>>(V, idx32, S, Q);
    final_kernel<<<BATCH / 4, 256, 0, stream>>>(dense, w0, w, V, idx32, S, Q, out);
}

// Round 2
// 413.957 us; speedup vs baseline: 1.0011x; 1.0011x over previous
//
#include <hip/hip_runtime.h>

#define NUM_DENSE 13
#define NUM_SPARSE 26
#define FEAT_NUM 40000
#define FEATURE_LENGTH (NUM_SPARSE * FEAT_NUM + NUM_DENSE)  // 1,040,013
#define KDIM 64
#define BATCH 4096
#define JHALF 13  // NUM_SPARSE / 2

// Kernel 0: build offset indices in [slot][batch] layout (int32) so that
// accum_kernel's index reads are fully coalesced.
__global__ void idx_kernel(const int* __restrict__ sp, int* __restrict__ idx32) {
    int tid = blockIdx.x * blockDim.x + threadIdx.x;  // tid = j*BATCH + b
    int j = tid >> 12;       // BATCH == 4096
    int b = tid & 4095;
    idx32[tid] = NUM_DENSE + j * FEAT_NUM + sp[b * NUM_SPARSE + j];
}

// Kernel 1: per (k, b, j-half) accumulate partial S and Q.
// grid (KDIM, 16, 2), block 256 -> 8192 waves = 32 waves/CU (full occupancy)
// to hide the ~200-900 cy scattered-gather latency.
// blockIdx.x = k keeps same-k blocks on one XCD (linear%8 == k%8): the active
// window is 8 k * 2 halves * 160KB = 2.5MB < 4MB per-XCD L2 -> ~2x line reuse.
__global__ __launch_bounds__(256) void accum_kernel(const float* __restrict__ V,
                                                    const int* __restrict__ idx32,
                                                    float* __restrict__ S,
                                                    float* __restrict__ Q) {
    const int k  = blockIdx.x;
    const int b  = blockIdx.y * 256 + threadIdx.x;
    const int jh = blockIdx.z;  // 0 or 1
    const float* __restrict__ Vk = V + (size_t)k * FEATURE_LENGTH;

    // Pre-load all 13 indices (coalesced, L2-hot) so the 13 scattered gathers
    // can all be in flight simultaneously.
    int ii[JHALF];
#pragma unroll
    for (int j = 0; j < JHALF; ++j) ii[j] = idx32[(jh * JHALF + j) * BATCH + b];

    float s = 0.f, q = 0.f;
#pragma unroll
    for (int j = 0; j < JHALF; ++j) {
        float v = Vk[ii[j]];
        s += v;
        q += v * v;
    }
    const int o = (jh * KDIM + k) * BATCH + b;  // [2][64][4096]
    S[o] = s;
    Q[o] = q;
}

// Kernel 2: one wave per batch row. lane = k.
__global__ void final_kernel(const float* __restrict__ dense,
                             const float* __restrict__ w0,
                             const float* __restrict__ w,
                             const float* __restrict__ V,
                             const int* __restrict__ idx32,
                             const float* __restrict__ S,
                             const float* __restrict__ Q,
                             float* __restrict__ out) {
    const int wave = threadIdx.x >> 6;
    const int lane = threadIdx.x & 63;
    const int b = blockIdx.x * 4 + wave;
    const int k = lane;
    const float* __restrict__ Vk = V + (size_t)k * FEATURE_LENGTH;

    float sv = S[k * BATCH + b] + S[(KDIM + k) * BATCH + b];
    float qv = Q[k * BATCH + b] + Q[(KDIM + k) * BATCH + b];
#pragma unroll
    for (int d = 0; d < NUM_DENSE; ++d) {
        float x  = dense[b * NUM_DENSE + d];  // wave-uniform broadcast
        float vv = Vk[d];                     // 64x13 values, L1/L2-hot
        sv += x * vv;
        qv += x * x * vv * vv;
    }
    float t = 0.5f * (sv * sv - qv);

    // first-order terms folded into the same reduction:
    if (lane < NUM_SPARSE) t += w[idx32[lane * BATCH + b]];          // sparse w gather
    if (lane >= 32 && lane < 32 + NUM_DENSE) {                       // dense w dot
        int d = lane - 32;
        t += dense[b * NUM_DENSE + d] * w[d];
    }

#pragma unroll
    for (int off = 32; off > 0; off >>= 1) t += __shfl_down(t, off);
    if (lane == 0) out[b] = w0[0] + t;
}

extern "C" void kernel_launch(void* const* d_in, const int* in_sizes, int n_in,
                              void* d_out, int out_size, void* d_ws, size_t ws_size,
                              hipStream_t stream) {
    const float* dense  = (const float*)d_in[0];
    const int*   sparse = (const int*)d_in[1];
    const float* w0     = (const float*)d_in[2];
    const float* w      = (const float*)d_in[3];
    const float* V      = (const float*)d_in[4];
    float* out = (float*)d_out;

    char* ws = (char*)d_ws;
    int*   idx32 = (int*)ws;                           // 26*4096*4 = 425,984 B
    float* S     = (float*)(ws + (1 << 19));           // 2*64*4096*4 = 2 MB
    float* Q     = (float*)(ws + (1 << 19) + 2 * KDIM * BATCH * 4);

    idx_kernel<<<(NUM_SPARSE * BATCH) / 256, 256, 0, stream>>>(sparse, idx32);
    accum_kernel<<<dim3(KDIM, 16, 2), 256, 0, stream>>>(V, idx32, S, Q);
    final_kernel<<<BATCH / 4, 256, 0, stream>>>(dense, w0, w, V, idx32, S, Q, out);
}

// Round 3
// 406.913 us; speedup vs baseline: 1.0184x; 1.0173x over previous
//
#include <hip/hip_runtime.h>

#define NUM_DENSE 13
#define NUM_SPARSE 26
#define FEAT_NUM 40000
#define FEATURE_LENGTH (NUM_SPARSE * FEAT_NUM + NUM_DENSE)  // 1,040,013
#define KDIM 64
#define BATCH 4096
#define QSIZE 10000   // quarter-window: 40KB LDS, stays under 64KB static limit
#define NT 1024

// Kernel 0: transpose sparse indices to [slot][batch] as raw per-slot values
// (0..39999) so accum gathers straight into the LDS window.
__global__ void transpose_kernel(const int* __restrict__ sp, int* __restrict__ sp_t) {
    int tid = blockIdx.x * blockDim.x + threadIdx.x;  // tid = j*BATCH + b
    int j = tid >> 12;
    int b = tid & 4095;
    sp_t[tid] = sp[b * NUM_SPARSE + j];
}

// Kernel 1: streaming accumulator. Block (k, g): g indexes a group of 6-7
// slots. For each slot j in the group, stream V[k, slot-j window] into LDS in
// four 10000-float quarters (fully coalesced float4, V read EXACTLY once
// device-wide), then all 4096 samples gather from LDS. This removes the
// L2-thrash over-fetch (~870 MB -> ~275 MB HBM).
__global__ __launch_bounds__(NT) void accum_kernel(const float* __restrict__ V,
                                                   const int* __restrict__ sp_t,
                                                   float* __restrict__ PS,
                                                   float* __restrict__ PQ) {
    __shared__ __align__(16) float win[QSIZE + 4];

    const int k = blockIdx.x;
    const int g = blockIdx.y;
    const int jstart = g * 7 - (g > 2 ? (g - 2) : 0);   // {0,7,14,20}
    const int jend   = jstart + (g < 2 ? 7 : 6);        // {7,14,20,26}
    const int tid = threadIdx.x;

    float sAcc[4] = {0.f, 0.f, 0.f, 0.f};
    float qAcc[4] = {0.f, 0.f, 0.f, 0.f};

    for (int j = jstart; j < jend; ++j) {
        // per-window sample indices (coalesced, L3-hot: 426 KB total)
        int spv[4];
#pragma unroll
        for (int r = 0; r < 4; ++r) spv[r] = sp_t[j * BATCH + tid + NT * r];

        for (int q = 0; q < 4; ++q) {
            const size_t s0 = (size_t)k * FEATURE_LENGTH + NUM_DENSE
                            + (size_t)j * FEAT_NUM + q * QSIZE;
            const float* __restrict__ Vq = V + s0;
            const int h   = (4 - ((int)(s0 & 3))) & 3;   // head to reach 16B align
            const int off = (4 - h) & 3;                  // LDS shift so body is 16B-aligned
            const int n4  = (QSIZE - h) >> 2;
            const int tl  = (QSIZE - h) & 3;

            __syncthreads();   // previous gather done before overwrite
            if (tid < h) win[off + tid] = Vq[tid];
            const float4* __restrict__ Vq4 = (const float4*)(Vq + h);
            for (int m = tid; m < n4; m += NT) {
                float4 v = Vq4[m];
                *reinterpret_cast<float4*>(&win[off + h + 4 * m]) = v;
            }
            const int ts = h + 4 * n4;
            if (tid < tl) win[off + ts + tid] = Vq[ts + tid];
            __syncthreads();

            const int q0 = q * QSIZE;
#pragma unroll
            for (int r = 0; r < 4; ++r) {
                int rel = spv[r] - q0;
                bool in = (rel >= 0) && (rel < QSIZE);
                int a = in ? (rel + off) : 0;             // masked lanes: broadcast read, free
                float v = win[a];
                v = in ? v : 0.f;
                sAcc[r] += v;
                qAcc[r] += v * v;
            }
        }
    }

    const int base = (g * KDIM + k) * BATCH + tid;        // [g][k][b]
#pragma unroll
    for (int r = 0; r < 4; ++r) {
        PS[base + NT * r] = sAcc[r];
        PQ[base + NT * r] = qAcc[r];
    }
}

// Kernel 2: one wave per batch row. lane = k.
__global__ void final_kernel(const float* __restrict__ dense,
                             const float* __restrict__ w0,
                             const float* __restrict__ w,
                             const float* __restrict__ V,
                             const int* __restrict__ sp_t,
                             const float* __restrict__ PS,
                             const float* __restrict__ PQ,
                             float* __restrict__ out) {
    const int wave = threadIdx.x >> 6;
    const int lane = threadIdx.x & 63;
    const int b = blockIdx.x * 4 + wave;
    const int k = lane;
    const float* __restrict__ Vk = V + (size_t)k * FEATURE_LENGTH;

    float sv = 0.f, qv = 0.f;
#pragma unroll
    for (int g = 0; g < 4; ++g) {
        sv += PS[(g * KDIM + k) * BATCH + b];
        qv += PQ[(g * KDIM + k) * BATCH + b];
    }
#pragma unroll
    for (int d = 0; d < NUM_DENSE; ++d) {
        float x  = dense[b * NUM_DENSE + d];  // wave-uniform broadcast
        float vv = Vk[d];
        sv += x * vv;
        qv += x * x * vv * vv;
    }
    float t = 0.5f * (sv * sv - qv);

    // first-order terms folded into the same reduction:
    if (lane < NUM_SPARSE)
        t += w[NUM_DENSE + lane * FEAT_NUM + sp_t[lane * BATCH + b]];
    if (lane >= 32 && lane < 32 + NUM_DENSE) {
        int d = lane - 32;
        t += dense[b * NUM_DENSE + d] * w[d];
    }

#pragma unroll
    for (int off = 32; off > 0; off >>= 1) t += __shfl_down(t, off);
    if (lane == 0) out[b] = w0[0] + t;
}

extern "C" void kernel_launch(void* const* d_in, const int* in_sizes, int n_in,
                              void* d_out, int out_size, void* d_ws, size_t ws_size,
                              hipStream_t stream) {
    const float* dense  = (const float*)d_in[0];
    const int*   sparse = (const int*)d_in[1];
    const float* w0     = (const float*)d_in[2];
    const float* w      = (const float*)d_in[3];
    const float* V      = (const float*)d_in[4];
    float* out = (float*)d_out;

    char* ws = (char*)d_ws;
    int*   sp_t = (int*)ws;                           // 26*4096*4 = 425,984 B
    float* PS   = (float*)(ws + (1 << 19));           // 4*64*4096*4 = 4 MB
    float* PQ   = (float*)(ws + (1 << 19) + 4 * KDIM * BATCH * 4);

    transpose_kernel<<<(NUM_SPARSE * BATCH) / 256, 256, 0, stream>>>(sparse, sp_t);
    accum_kernel<<<dim3(KDIM, 4), NT, 0, stream>>>(V, sp_t, PS, PQ);
    final_kernel<<<BATCH / 4, 256, 0, stream>>>(dense, w0, w, V, sp_t, PS, PQ, out);
}

// Round 4
// 401.166 us; speedup vs baseline: 1.0330x; 1.0143x over previous
//
#include <hip/hip_runtime.h>

#define NUM_DENSE 13
#define NUM_SPARSE 26
#define FEAT_NUM 40000
#define FEATURE_LENGTH (NUM_SPARSE * FEAT_NUM + NUM_DENSE)  // 1,040,013
#define KDIM 64
#define BATCH 4096
#define QSIZE 8000          // floats per LDS chunk: 5 chunks per 40000-window
#define NCHUNK 5
#define LDSN (QSIZE + 4)    // + up-to-3 alignment shift, padded
#define NT 1024

// Kernel 0: transpose sparse indices to [slot][batch] (raw 0..39999 values).
__global__ void transpose_kernel(const int* __restrict__ sp, int* __restrict__ sp_t) {
    int tid = blockIdx.x * blockDim.x + threadIdx.x;  // tid = j*BATCH + b
    int j = tid >> 12;
    int b = tid & 4095;
    sp_t[tid] = sp[b * NUM_SPARSE + j];
}

// Kernel 1: software-pipelined streaming accumulator.
// Block (k, g): streams V[k, windows jstart..jend) through a double-buffered
// 32KB LDS chunk. Per iteration: issue global loads for chunk s+1, gather
// chunk s from LDS (overlapped with the in-flight loads), ds_write s+1,
// barrier. V is read exactly once device-wide (266 MB -> ~42 us floor).
__global__ __launch_bounds__(NT) void accum_kernel(const float* __restrict__ V,
                                                   const int* __restrict__ sp_t,
                                                   float* __restrict__ PS,
                                                   float* __restrict__ PQ) {
    __shared__ __align__(16) float buf[2][LDSN];   // 2 x 32,016 B = 64,032 B

    const int k = blockIdx.x;
    const int g = blockIdx.y;
    const int jstart = (g * NUM_SPARSE) / 4;        // 0,6,13,19
    const int jend   = ((g + 1) * NUM_SPARSE) / 4;  // 6,13,19,26
    const int tid = threadIdx.x;

    const size_t kbase = (size_t)k * FEATURE_LENGTH + NUM_DENSE;
    const int a   = (int)(kbase & 3);               // window starts = kbase mod 4
    const int nl4 = (QSIZE + a + 3) >> 2;           // float4 loads per chunk (2000/2001)
    // NOTE: a>0 over-reads <=3 floats past the window; a>0 only for k<63 (in-bounds).
    // k=63 has a==0 and its last chunk ends exactly at V's end. No OOB.

    const int nstage = (jend - jstart) * NCHUNK;

    float sAcc[4] = {0.f, 0.f, 0.f, 0.f};
    float qAcc[4] = {0.f, 0.f, 0.f, 0.f};

    int j = jstart, q = 0;
    int spv[4];
#pragma unroll
    for (int r = 0; r < 4; ++r) spv[r] = sp_t[j * BATCH + tid + NT * r];

    // prologue: load stage 0 into buf[0]
    {
        const float4* __restrict__ g4 =
            (const float4*)(V + (kbase + (size_t)j * FEAT_NUM) - a);
        float4 v0 = g4[tid];
        bool p1 = (tid + NT) < nl4;
        float4 v1;
        if (p1) v1 = g4[tid + NT];
        *reinterpret_cast<float4*>(&buf[0][4 * tid]) = v0;
        if (p1) *reinterpret_cast<float4*>(&buf[0][4 * (tid + NT)]) = v1;
    }
    __syncthreads();

    int cur = 0;
    for (int s = 0; s < nstage; ++s) {
        // next stage coords
        int qn = q + 1, jn = j;
        if (qn == NCHUNK) { qn = 0; jn = j + 1; }
        const bool hasNext = (s + 1 < nstage);

        // 1) issue global loads for stage s+1 (async; overlap with gather below)
        float4 v0, v1;
        bool p1 = false;
        if (hasNext) {
            const float4* __restrict__ g4 =
                (const float4*)(V + (kbase + (size_t)jn * FEAT_NUM + (size_t)qn * QSIZE) - a);
            v0 = g4[tid];
            p1 = (tid + NT) < nl4;
            if (p1) v1 = g4[tid + NT];
        }

        // 2) gather current stage from LDS
        {
            const int q0 = q * QSIZE;
#pragma unroll
            for (int r = 0; r < 4; ++r) {
                int rel = spv[r] - q0;
                bool in = (rel >= 0) && (rel < QSIZE);
                int addr = in ? (rel + a) : 0;     // masked lanes: broadcast read
                float v = buf[cur][addr];
                v = in ? v : 0.f;
                sAcc[r] += v;
                qAcc[r] += v * v;
            }
        }

        // 3) commit stage s+1 into the other buffer (waits vmcnt here, after gather)
        if (hasNext) {
            *reinterpret_cast<float4*>(&buf[cur ^ 1][4 * tid]) = v0;
            if (p1) *reinterpret_cast<float4*>(&buf[cur ^ 1][4 * (tid + NT)]) = v1;
        }
        __syncthreads();
        cur ^= 1;

        // 4) window rollover: refresh sample indices (used first in iter s+1's gather)
        if (hasNext && jn != j) {
#pragma unroll
            for (int r = 0; r < 4; ++r) spv[r] = sp_t[jn * BATCH + tid + NT * r];
        }
        j = jn; q = qn;
    }

    const int base = (g * KDIM + k) * BATCH + tid;   // [g][k][b]
#pragma unroll
    for (int r = 0; r < 4; ++r) {
        PS[base + NT * r] = sAcc[r];
        PQ[base + NT * r] = qAcc[r];
    }
}

// Kernel 2: thread = b (coalesced PS/PQ reads), k-range split over 4 waves,
// LDS reduce. grid 64 blocks x 256 threads.
__global__ __launch_bounds__(256) void final_kernel(const float* __restrict__ dense,
                                                    const float* __restrict__ w0,
                                                    const float* __restrict__ w,
                                                    const float* __restrict__ V,
                                                    const int* __restrict__ sp_t,
                                                    const float* __restrict__ PS,
                                                    const float* __restrict__ PQ,
                                                    float* __restrict__ out) {
    __shared__ float red[4][64];
    const int wv = threadIdx.x >> 6;
    const int ln = threadIdx.x & 63;
    const int b  = blockIdx.x * 64 + ln;

    float x[NUM_DENSE], x2[NUM_DENSE];
#pragma unroll
    for (int d = 0; d < NUM_DENSE; ++d) {
        x[d]  = dense[b * NUM_DENSE + d];
        x2[d] = x[d] * x[d];
    }

    float t = 0.f;
    const int k0 = wv * 16;
#pragma unroll 4
    for (int kk = 0; kk < 16; ++kk) {
        const int k = k0 + kk;
        float sv = 0.f, qv = 0.f;
#pragma unroll
        for (int g = 0; g < 4; ++g) {
            sv += PS[((g << 6) + k) * BATCH + b];   // coalesced: consecutive ln -> consecutive b
            qv += PQ[((g << 6) + k) * BATCH + b];
        }
        const float* __restrict__ Vk = V + (size_t)k * FEATURE_LENGTH;
#pragma unroll
        for (int d = 0; d < NUM_DENSE; ++d) {
            float vv = Vk[d];                       // wave-uniform scalar, L1-hot
            sv += x[d] * vv;
            qv += x2[d] * vv * vv;
        }
        t += sv * sv - qv;
    }
    t *= 0.5f;

    // first-order sparse: slots strided across the 4 waves
    for (int jj = wv; jj < NUM_SPARSE; jj += 4)
        t += w[NUM_DENSE + jj * FEAT_NUM + sp_t[jj * BATCH + b]];
    // first-order dense: wave 0 only
    if (wv == 0) {
#pragma unroll
        for (int d = 0; d < NUM_DENSE; ++d) t += x[d] * w[d];
    }

    red[wv][ln] = t;
    __syncthreads();
    if (wv == 0)
        out[b] = w0[0] + red[0][ln] + red[1][ln] + red[2][ln] + red[3][ln];
}

extern "C" void kernel_launch(void* const* d_in, const int* in_sizes, int n_in,
                              void* d_out, int out_size, void* d_ws, size_t ws_size,
                              hipStream_t stream) {
    const float* dense  = (const float*)d_in[0];
    const int*   sparse = (const int*)d_in[1];
    const float* w0     = (const float*)d_in[2];
    const float* w      = (const float*)d_in[3];
    const float* V      = (const float*)d_in[4];
    float* out = (float*)d_out;

    char* ws = (char*)d_ws;
    int*   sp_t = (int*)ws;                           // 26*4096*4 = 425,984 B
    float* PS   = (float*)(ws + (1 << 19));           // 4*64*4096*4 = 4 MB
    float* PQ   = (float*)(ws + (1 << 19) + 4 * KDIM * BATCH * 4);

    transpose_kernel<<<(NUM_SPARSE * BATCH) / 256, 256, 0, stream>>>(sparse, sp_t);
    accum_kernel<<<dim3(KDIM, 4), NT, 0, stream>>>(V, sp_t, PS, PQ);
    final_kernel<<<BATCH / 64, 256, 0, stream>>>(dense, w0, w, V, sp_t, PS, PQ, out);
}

// Round 5
// 391.773 us; speedup vs baseline: 1.0578x; 1.0240x over previous
//
#include <hip/hip_runtime.h>

#define NUM_DENSE 13
#define NUM_SPARSE 26
#define FEAT_NUM 40000
#define FEATURE_LENGTH (NUM_SPARSE * FEAT_NUM + NUM_DENSE)  // 1,040,013
#define KDIM 64
#define BATCH 4096
#define QSIZE 8000          // floats per LDS chunk: 5 chunks per 40000-window
#define NCHUNK 5
#define LDSN (QSIZE + 4)    // + up-to-3 alignment shift
#define NT 1024
#define NG 8                // j-groups -> 512 blocks = 2 blocks/CU (bubble hiding)

// Kernel 0: transpose sparse indices to [slot][batch] (raw 0..39999 values).
__global__ void transpose_kernel(const int* __restrict__ sp, int* __restrict__ sp_t) {
    int tid = blockIdx.x * blockDim.x + threadIdx.x;  // tid = j*BATCH + b
    int j = tid >> 12;
    int b = tid & 4095;
    sp_t[tid] = sp[b * NUM_SPARSE + j];
}

// async global->LDS, 16B per lane; HW dest = wave-uniform(base) + lane*16.
// We pass per-lane pointers where lane L's value == base + L*16, matching HW.
__device__ __forceinline__ void load_lds16(const float4* g, float* l) {
    __builtin_amdgcn_global_load_lds(
        (const __attribute__((address_space(1))) void*)g,
        (__attribute__((address_space(3))) void*)l, 16, 0, 0);
}

// Kernel 1: double-buffered streaming accumulator with async LDS staging.
// Block (k, g): streams V[k, windows of group g] through 2x32KB LDS chunks.
// 512 blocks -> 2 blocks/CU: the partner block's waves execute during this
// block's barrier vmcnt-drain, removing the ~1000cy/stage bubble of R4.
// V is read exactly once device-wide (266 MB -> ~42 us floor).
__global__ __launch_bounds__(NT) void accum_kernel(const float* __restrict__ V,
                                                   const int* __restrict__ sp_t,
                                                   float* __restrict__ PS,
                                                   float* __restrict__ PQ) {
    __shared__ __align__(16) float buf[2][LDSN];   // 2 x 32,016 B

    const int k = blockIdx.x;
    const int g = blockIdx.y;
    const int tid = threadIdx.x;
    const int jstart = (g * NUM_SPARSE) / NG;        // 0,3,6,9,13,16,19,22
    const int jend   = ((g + 1) * NUM_SPARSE) / NG;  // 3,6,9,13,16,19,22,26

    const size_t kbase = (size_t)k * FEATURE_LENGTH + NUM_DENSE;
    const int a   = (int)(kbase & 3);        // = (k+1)&3; k=63 -> 0 (exact end, no OOB)
    const int nl4 = (QSIZE + a + 3) >> 2;    // 2000 or 2001 float4 loads per chunk
    const int nstage = (jend - jstart) * NCHUNK;

    float sAcc[4] = {0.f, 0.f, 0.f, 0.f};
    float qAcc[4] = {0.f, 0.f, 0.f, 0.f};

    int j = jstart, q = 0;
    int spv[4];
#pragma unroll
    for (int r = 0; r < 4; ++r) spv[r] = sp_t[j * BATCH + tid + NT * r];

    // prologue: async-load stage 0 into buf[0]
    {
        const float4* __restrict__ g4 =
            (const float4*)(V + (kbase + (size_t)j * FEAT_NUM) - a);
        load_lds16(g4 + tid, &buf[0][4 * tid]);
        if (1024 + tid < nl4) load_lds16(g4 + 1024 + tid, &buf[0][4 * (1024 + tid)]);
    }
    __syncthreads();   // vmcnt drain: stage 0 resident

    int cur = 0;
    for (int s = 0; s < nstage; ++s) {
        int qn = q + 1, jn = j;
        if (qn == NCHUNK) { qn = 0; jn = j + 1; }
        const bool hasNext = (s + 1 < nstage);

        // 1) issue async loads for stage s+1 into the other buffer
        if (hasNext) {
            const float4* __restrict__ g4 =
                (const float4*)(V + (kbase + (size_t)jn * FEAT_NUM + (size_t)qn * QSIZE) - a);
            float* lb = &buf[cur ^ 1][0];
            load_lds16(g4 + tid, lb + 4 * tid);
            if (1024 + tid < nl4) load_lds16(g4 + 1024 + tid, lb + 4 * (1024 + tid));
        }

        // 2) gather current stage from LDS (loads fly meanwhile)
        {
            const int q0 = q * QSIZE;
#pragma unroll
            for (int r = 0; r < 4; ++r) {
                int rel = spv[r] - q0;
                bool in = (rel >= 0) && (rel < QSIZE);
                int addr = in ? (rel + a) : 0;   // masked lanes: broadcast read, free
                float v = buf[cur][addr];
                v = in ? v : 0.f;
                sAcc[r] += v;
                qAcc[r] += v * v;
            }
        }

        __syncthreads();   // drains vmcnt -> stage s+1 resident for next iter

        // 3) window rollover: refresh sample indices for the next gather
        if (hasNext && jn != j) {
#pragma unroll
            for (int r = 0; r < 4; ++r) spv[r] = sp_t[jn * BATCH + tid + NT * r];
        }
        j = jn; q = qn; cur ^= 1;
    }

    const int base = (g * KDIM + k) * BATCH + tid;   // [g][k][b]
#pragma unroll
    for (int r = 0; r < 4; ++r) {
        PS[base + NT * r] = sAcc[r];
        PQ[base + NT * r] = qAcc[r];
    }
}

// Kernel 2: 256 blocks x 256 threads. Block = 16 batch rows; thread (bi, ki)
// covers b = blk*16+bi and 4 k values; LDS-reduce over ki; 16 threads finish
// first-order terms + output. Full-device BW on the 16.8 MB PS/PQ read.
__global__ __launch_bounds__(256) void final_kernel(const float* __restrict__ dense,
                                                    const float* __restrict__ w0,
                                                    const float* __restrict__ w,
                                                    const float* __restrict__ V,
                                                    const int* __restrict__ sp_t,
                                                    const float* __restrict__ PS,
                                                    const float* __restrict__ PQ,
                                                    float* __restrict__ out) {
    __shared__ float red[16][17];
    const int tid = threadIdx.x;
    const int bi  = tid & 15;
    const int ki  = tid >> 4;                 // 0..15
    const int b   = blockIdx.x * 16 + bi;

    float x[NUM_DENSE], x2[NUM_DENSE];
#pragma unroll
    for (int d = 0; d < NUM_DENSE; ++d) {
        x[d]  = dense[b * NUM_DENSE + d];     // L1-hot (16 b per block)
        x2[d] = x[d] * x[d];
    }

    float t = 0.f;
#pragma unroll
    for (int kk = 0; kk < 4; ++kk) {
        const int k = ki * 4 + kk;
        float sv = 0.f, qv = 0.f;
#pragma unroll
        for (int g = 0; g < NG; ++g) {
            sv += PS[((g << 6) + k) * BATCH + b];   // 16-lane 64B segments
            qv += PQ[((g << 6) + k) * BATCH + b];
        }
        const float* __restrict__ Vk = V + (size_t)k * FEATURE_LENGTH;
#pragma unroll
        for (int d = 0; d < NUM_DENSE; ++d) {
            float vv = Vk[d];                 // 64x13 distinct values, L2-hot
            sv += x[d] * vv;
            qv += x2[d] * vv * vv;
        }
        t += sv * sv - qv;
    }
    red[bi][ki] = 0.5f * t;
    __syncthreads();

    if (tid < 16) {                           // tid == bi, one thread per row
        const int bb = blockIdx.x * 16 + tid;
        float acc = w0[0];
#pragma unroll
        for (int i = 0; i < 16; ++i) acc += red[tid][i];
        // first-order sparse (w gather, 4MB table, L3-hot)
#pragma unroll
        for (int j = 0; j < NUM_SPARSE; ++j)
            acc += w[NUM_DENSE + j * FEAT_NUM + sp_t[j * BATCH + bb]];
        // first-order dense
#pragma unroll
        for (int d = 0; d < NUM_DENSE; ++d) acc += x[d] * w[d];
        out[bb] = acc;
    }
}

extern "C" void kernel_launch(void* const* d_in, const int* in_sizes, int n_in,
                              void* d_out, int out_size, void* d_ws, size_t ws_size,
                              hipStream_t stream) {
    const float* dense  = (const float*)d_in[0];
    const int*   sparse = (const int*)d_in[1];
    const float* w0     = (const float*)d_in[2];
    const float* w      = (const float*)d_in[3];
    const float* V      = (const float*)d_in[4];
    float* out = (float*)d_out;

    char* ws = (char*)d_ws;
    int*   sp_t = (int*)ws;                               // 26*4096*4 = 425,984 B
    float* PS   = (float*)(ws + (1 << 20));               // 8*64*4096*4 = 8.39 MB
    float* PQ   = (float*)(ws + (1 << 20) + NG * KDIM * BATCH * 4);

    transpose_kernel<<<(NUM_SPARSE * BATCH) / 256, 256, 0, stream>>>(sparse, sp_t);
    accum_kernel<<<dim3(KDIM, NG), NT, 0, stream>>>(V, sp_t, PS, PQ);
    final_kernel<<<BATCH / 16, 256, 0, stream>>>(dense, w0, w, V, sp_t, PS, PQ, out);
}